// Round 2
// baseline (164244.556 us; speedup 1.0000x reference)
//
#include <hip/hip_runtime.h>
#include <cmath>

// MARNN scan, multi-kernel stream-ordered version (no cooperative launch).
// Per step t: K_A (argmax + h_ent gather + gates1 GEMM, K-split w/ f64 atomics)
//          -> K_B (pre GEMM with on-the-fly gating, K-split w/ f64 atomics)
//          -> K_C (epilogue: LSTM cell, outputs, wv/head GEMVs, hmem update).
// Score (argmax input) for all t is precomputed in fp64 and stashed in
// out[t,b,512:640] (the r-slot), which K_C overwrites with the real r AFTER
// K_A has consumed it. c-contribution to score(t+1) is added by K_C(t).

#define TT 256
#define BB 256
#define XD 256
#define HD 512
#define RD 128
#define MD 128
#define N1 640    // R + H      (gates1 width)
#define NP 2176   // R + 4H     (pre width)
#define NTHR 256

// ---- workspace layout (float offsets), total 5,964,288 floats ~ 23.9 MiB ----
#define OFF_C     0u         // cbuf  [B,H]
#define OFF_HMEM  131072u    // hmem  [B,M,R]
#define OFF_HENT  4325376u   // h_ent [B,R]
#define OFF_SEL   4358144u   // selbuf[B] int
#define OFF_FXT   4358400u   // fcxT  [256,128]  fc_w[:, :256]^T
#define OFF_TWT   4391168u   // transT[512,128]  trans_w^T
#define OFF_FWT   4456704u   // fcwcT [512,128]  fc_w[:,256:768]^T
#define OFF_HEAD0 4522240u   // head0 [M] double (c0 @ fc_wc^T)
#define OFF_G1D   4522496u   // g1d   [B,N1] double accum
#define OFF_PRED  4850176u   // pred  [B,NP] double accum

struct SMemG { float As[16*132]; float Bs[16*128]; int sel[128]; };
struct SMemE { float c[4*512]; float wv[4*128]; };
union  SMemU { SMemG g; SMemE e; };

__device__ __forceinline__ float sigm(float z){ return 1.0f/(1.0f + expf(-z)); }
__device__ __forceinline__ float4 ld4(const float* p){ return *(const float4*)p; }

// 128x128 tile GEMM, 256 threads, 8x8 per thread, K chunks of 16.
template<class LA, class LB>
__device__ __forceinline__ void gemm_tile(SMemU& smu, int tid, int kbeg, int kend,
                                          LA loadA, LB loadB, float acc[8][8])
{
  SMemG& g = smu.g;
  const int tx = tid & 15, ty = tid >> 4;
  for (int k0 = kbeg; k0 < kend; k0 += 16) {
    __syncthreads();
    #pragma unroll
    for (int rep = 0; rep < 2; ++rep) {       // stage A: 128 rows x 16 k (k-major)
      int idx = tid + rep*NTHR;
      int row = idx >> 2, kq = (idx & 3) << 2;
      float4 v = loadA(row, k0 + kq);
      g.As[(kq+0)*132 + row] = v.x;
      g.As[(kq+1)*132 + row] = v.y;
      g.As[(kq+2)*132 + row] = v.z;
      g.As[(kq+3)*132 + row] = v.w;
    }
    #pragma unroll
    for (int rep = 0; rep < 2; ++rep) {       // stage B: 16 k x 128 n
      int idx = tid + rep*NTHR;
      int kk = idx >> 5, nq = (idx & 31) << 2;
      float4 v = loadB(k0 + kk, nq);
      *(float4*)&g.Bs[kk*128 + nq] = v;
    }
    __syncthreads();
    #pragma unroll
    for (int k = 0; k < 16; ++k) {
      float a[8], b[8];
      *(float4*)&a[0] = ld4(&g.As[k*132 + ty*8]);
      *(float4*)&a[4] = ld4(&g.As[k*132 + ty*8 + 4]);
      *(float4*)&b[0] = ld4(&g.Bs[k*128 + tx*8]);
      *(float4*)&b[4] = ld4(&g.Bs[k*128 + tx*8 + 4]);
      #pragma unroll
      for (int i = 0; i < 8; ++i)
        #pragma unroll
        for (int j = 0; j < 8; ++j)
          acc[i][j] = fmaf(a[i], b[j], acc[i][j]);
    }
  }
}

// ---------- init: state, transposes, head0 (fp64) ----------
__global__ __launch_bounds__(NTHR)
void k_pre(const float* __restrict__ fc_w, const float* __restrict__ trans_w,
           const float* __restrict__ c_bias, const float* __restrict__ hmem_bias,
           float* __restrict__ ws)
{
  float*  cbuf   = ws + OFF_C;
  float*  hmem   = ws + OFF_HMEM;
  float*  fcxT   = ws + OFF_FXT;
  float*  transT = ws + OFF_TWT;
  float*  fcwcT  = ws + OFF_FWT;
  double* head0d = (double*)(ws + OFF_HEAD0);
  double* g1d    = (double*)(ws + OFF_G1D);
  double* pred   = (double*)(ws + OFF_PRED);

  const int gt = blockIdx.x*NTHR + threadIdx.x, GT = gridDim.x*NTHR;
  for (int i = gt; i < BB*HD;    i += GT) cbuf[i] = (float)tanh((double)c_bias[i & 511]);
  for (int i = gt; i < BB*MD*RD; i += GT) hmem[i] = hmem_bias[i & (MD*RD - 1)];
  for (int i = gt; i < BB*NP;    i += GT) pred[i] = 0.0;
  for (int i = gt; i < BB*N1;    i += GT) g1d[i]  = 0.0;
  for (int i = gt; i < XD*128;   i += GT) { int k=i>>7, m=i&127; fcxT[i]  = fc_w[(size_t)m*768 + k]; }
  for (int i = gt; i < HD*128;   i += GT) { int k=i>>7, o=i&127; transT[i] = trans_w[(size_t)o*512 + k];
                                            fcwcT[i]  = fc_w[(size_t)o*768 + 256 + k]; }
  if (blockIdx.x == 0 && threadIdx.x < 128) {
    double a = 0.0;
    for (int k = 0; k < 512; ++k)
      a += tanh((double)c_bias[k]) * (double)fc_w[(size_t)threadIdx.x*768 + 256 + k];
    head0d[threadIdx.x] = a;
  }
}

// ---------- score: out[t,b,512+m] = fp64(x-part head + fc_b + gumbel) ----------
__global__ __launch_bounds__(NTHR)
void k_score(const float* __restrict__ x, const float* __restrict__ noise,
             const float* __restrict__ fc_b, const float* __restrict__ ws_fcxT,
             float* __restrict__ out)
{
  __shared__ float xs[16*256];
  const int tid = threadIdx.x;
  const int rbase = blockIdx.x * 16;           // 4096 blocks x 16 rows
  for (int i = tid; i < 16*64; i += NTHR) {    // stage 16 rows of x (float4)
    int row = i >> 6, kq = (i & 63) << 2;
    *(float4*)&xs[row*256 + kq] = ld4(x + (size_t)(rbase + row)*XD + kq);
  }
  __syncthreads();
  const int m = tid & 127, r0 = (tid >> 7) * 8;
  double acc[8] = {};
  for (int k = 0; k < 256; ++k) {
    double wk = (double)ws_fcxT[k*128 + m];
    #pragma unroll
    for (int r = 0; r < 8; ++r) acc[r] += wk * (double)xs[(r0+r)*256 + k];
  }
  #pragma unroll
  for (int r = 0; r < 8; ++r) {
    size_t grow = (size_t)rbase + r0 + r;
    double g   = (double)noise[grow*MD + m];
    double gum = -log(1e-20 - log(1e-20 + g));
    out[grow*640 + 512 + m] = (float)(acc[r] + (double)fc_b[m] + gum);
  }
}

// ---------- K_A: argmax + h_ent gather + gates1 GEMM (280 blocks) ----------
__global__ __launch_bounds__(NTHR)
void k_gates1(const float* __restrict__ x, const float* __restrict__ W_full1,
              const float* __restrict__ out, float* __restrict__ ws, int t)
{
  __shared__ SMemU sm;
  const int tid = threadIdx.x, bid = blockIdx.x;
  float*  cbuf   = ws + OFF_C;
  float*  hmem   = ws + OFF_HMEM;
  float*  h_ent  = ws + OFF_HENT;
  int*    selbuf = (int*)(ws + OFF_SEL);
  double* head0d = (double*)(ws + OFF_HEAD0);
  double* g1d    = (double*)(ws + OFF_G1D);

  int mt = bid / 140, rest = bid % 140, nt = rest / 28, ks = rest % 28;
  int r0 = mt*128, n0 = nt*128, k0 = ks*32;

  if (k0 >= 768) {                             // piece-2 chunks need the argmax
    if (tid < 128) {
      const float* sc = out + ((size_t)t*BB + r0 + tid)*640 + 512;
      int bi = 0;
      if (t == 0) {
        double best = -1e300;
        for (int m = 0; m < 128; ++m) { double v = (double)sc[m] + head0d[m]; if (v > best) { best = v; bi = m; } }
      } else {
        float best = -3.4e38f;
        for (int m = 0; m < 128; ++m) { float v = sc[m]; if (v > best) { best = v; bi = m; } }
      }
      sm.g.sel[tid] = bi;
    }
    __syncthreads();
    if (ks == 27 && nt == 0) {                 // designated writer per row-group
      if (tid < 128) selbuf[r0 + tid] = sm.g.sel[tid];
      for (int idx = tid; idx < 128*128; idx += NTHR) {
        int row = idx >> 7, rr = idx & 127;
        h_ent[(size_t)(r0+row)*RD + rr] = hmem[((size_t)(r0+row)*MD + sm.g.sel[row])*RD + rr];
      }
    }
  }
  float acc[8][8] = {};
  int piece = (k0 < 256) ? 0 : (k0 < 768) ? 1 : 2;
  auto lA = [&](int row, int k)->float4 {
    int b = r0 + row;
    if (piece == 0) return ld4(x + ((size_t)t*BB + b)*XD + k);
    if (piece == 1) return ld4(cbuf + (size_t)b*HD + (k - XD));
    return ld4(hmem + ((size_t)b*MD + sm.g.sel[row])*RD + (k - 768));
  };
  auto lB = [&](int k, int nq)->float4 { return ld4(W_full1 + (size_t)k*N1 + n0 + nq); };
  gemm_tile(sm, tid, k0, k0 + 32, lA, lB, acc);
  const int tx = tid & 15, ty = tid >> 4;
  #pragma unroll
  for (int i = 0; i < 8; ++i)
    #pragma unroll
    for (int j = 0; j < 8; ++j)
      atomicAdd(&g1d[(size_t)(r0 + ty*8 + i)*N1 + n0 + tx*8 + j], (double)acc[i][j]);
}

// ---------- K_B: pre GEMM with on-the-fly gating (476 blocks) ----------
__global__ __launch_bounds__(NTHR)
void k_pre_gemm(const float* __restrict__ x, const float* __restrict__ W_full,
                const float* __restrict__ bias1, float* __restrict__ ws, int t)
{
  __shared__ SMemU sm;
  const int tid = threadIdx.x, bid = blockIdx.x;
  float*  cbuf  = ws + OFF_C;
  float*  h_ent = ws + OFF_HENT;
  double* g1d   = (double*)(ws + OFF_G1D);
  double* pred  = (double*)(ws + OFF_PRED);

  int mt = bid / 238, rest = bid % 238, nt = rest / 14, ks = rest % 14;
  int r0 = mt*128, n0 = nt*128, k0 = ks*64;
  float acc[8][8] = {};
  int piece = (k0 < 256) ? 0 : (k0 < 768) ? 1 : 2;
  auto lA = [&](int row, int k)->float4 {
    int b = r0 + row;
    if (piece == 0) return ld4(x + ((size_t)t*BB + b)*XD + k);
    if (piece == 1) {
      int j = k - XD;
      float4 cv = ld4(cbuf + (size_t)b*HD + j);
      const double* gp = g1d + (size_t)b*N1 + j;
      cv.x *= sigm((float)gp[0] + bias1[j+0]);
      cv.y *= sigm((float)gp[1] + bias1[j+1]);
      cv.z *= sigm((float)gp[2] + bias1[j+2]);
      cv.w *= sigm((float)gp[3] + bias1[j+3]);
      return cv;
    }
    int j = k - 768;
    float4 hv = ld4(h_ent + (size_t)b*RD + j);
    const double* gp = g1d + (size_t)b*N1 + 512 + j;
    hv.x *= sigm((float)gp[0] + bias1[512+j+0]);
    hv.y *= sigm((float)gp[1] + bias1[512+j+1]);
    hv.z *= sigm((float)gp[2] + bias1[512+j+2]);
    hv.w *= sigm((float)gp[3] + bias1[512+j+3]);
    return hv;
  };
  auto lB = [&](int k, int nq)->float4 { return ld4(W_full + (size_t)k*NP + n0 + nq); };
  gemm_tile(sm, tid, k0, k0 + 64, lA, lB, acc);
  const int tx = tid & 15, ty = tid >> 4;
  #pragma unroll
  for (int i = 0; i < 8; ++i)
    #pragma unroll
    for (int j = 0; j < 8; ++j)
      atomicAdd(&pred[(size_t)(r0 + ty*8 + i)*NP + n0 + tx*8 + j], (double)acc[i][j]);
}

// ---------- K_C: epilogue (64 blocks x 4 batch rows) ----------
__global__ __launch_bounds__(NTHR)
void k_epi(const float* __restrict__ bias, const float* __restrict__ trans_b,
           float* __restrict__ out, float* __restrict__ ws, int t)
{
  __shared__ SMemE sm;
  const int tid = threadIdx.x, b0 = blockIdx.x*4;
  float*  cbuf   = ws + OFF_C;
  float*  hmem   = ws + OFF_HMEM;
  float*  h_ent  = ws + OFF_HENT;
  int*    selbuf = (int*)(ws + OFF_SEL);
  float*  transT = ws + OFF_TWT;
  float*  fcwcT  = ws + OFF_FWT;
  double* g1d    = (double*)(ws + OFF_G1D);
  double* pred   = (double*)(ws + OFF_PRED);

  for (int idx = tid; idx < 4*512; idx += NTHR) {
    int br = idx >> 9, hh = idx & 511, b = b0 + br;
    double* pr = pred + (size_t)b*NP;
    float iv = (float)pr[hh]        + bias[hh];
    float jv = (float)pr[512 + hh]  + bias[512 + hh];
    float fv = (float)pr[1024 + hh] + bias[1024 + hh];
    float ov = (float)pr[1536 + hh] + bias[1536 + hh];
    float cold = cbuf[(size_t)b*HD + hh];
    float nc = tanhf(cold*sigm(fv + 1.0f) + sigm(iv)*tanhf(jv));
    cbuf[(size_t)b*HD + hh] = nc;
    sm.c[br*512 + hh] = nc;
    out[((size_t)t*BB + b)*640 + hh] = nc * sigm(ov);
    pr[hh] = 0.0; pr[512+hh] = 0.0; pr[1024+hh] = 0.0; pr[1536+hh] = 0.0;
  }
  for (int idx = tid; idx < 4*128; idx += NTHR) {
    int br = idx >> 7, rr = idx & 127, b = b0 + br;
    float om = (float)pred[(size_t)b*NP + 2048 + rr] + bias[2048 + rr];
    out[((size_t)t*BB + b)*640 + 512 + rr] = h_ent[(size_t)b*RD + rr] * sigm(om);
    pred[(size_t)b*NP + 2048 + rr] = 0.0;
  }
  for (int idx = tid; idx < 4*640; idx += NTHR) {
    int br = idx / 640, j = idx - br*640;
    g1d[(size_t)(b0+br)*N1 + j] = 0.0;
  }
  __syncthreads();
  if (t < TT-1) {
    // wv = new_c @ trans_w^T + trans_b ;  score(t+1) += new_c @ fc_wc^T   (fp64 acc)
    int o = tid & 127, mat = tid >> 7;
    const float* WT = mat ? fcwcT : transT;
    double a0=0., a1=0., a2=0., a3=0.;
    for (int k = 0; k < 512; k += 4) {
      float w0 = WT[(k+0)*128 + o], w1 = WT[(k+1)*128 + o];
      float w2 = WT[(k+2)*128 + o], w3 = WT[(k+3)*128 + o];
      float4 c0v = ld4(&sm.c[0*512 + k]);
      float4 c1v = ld4(&sm.c[1*512 + k]);
      float4 c2v = ld4(&sm.c[2*512 + k]);
      float4 c3v = ld4(&sm.c[3*512 + k]);
      a0 += (double)w0*c0v.x + (double)w1*c0v.y + (double)w2*c0v.z + (double)w3*c0v.w;
      a1 += (double)w0*c1v.x + (double)w1*c1v.y + (double)w2*c1v.z + (double)w3*c1v.w;
      a2 += (double)w0*c2v.x + (double)w1*c2v.y + (double)w2*c2v.z + (double)w3*c2v.w;
      a3 += (double)w0*c3v.x + (double)w1*c3v.y + (double)w2*c3v.z + (double)w3*c3v.w;
    }
    if (mat == 0) {
      sm.wv[0*128+o] = (float)(a0 + (double)trans_b[o]);
      sm.wv[1*128+o] = (float)(a1 + (double)trans_b[o]);
      sm.wv[2*128+o] = (float)(a2 + (double)trans_b[o]);
      sm.wv[3*128+o] = (float)(a3 + (double)trans_b[o]);
    } else {
      float* sx = out + ((size_t)(t+1)*BB)*640;
      sx[(size_t)(b0+0)*640 + 512 + o] = (float)((double)sx[(size_t)(b0+0)*640 + 512 + o] + a0);
      sx[(size_t)(b0+1)*640 + 512 + o] = (float)((double)sx[(size_t)(b0+1)*640 + 512 + o] + a1);
      sx[(size_t)(b0+2)*640 + 512 + o] = (float)((double)sx[(size_t)(b0+2)*640 + 512 + o] + a2);
      sx[(size_t)(b0+3)*640 + 512 + o] = (float)((double)sx[(size_t)(b0+3)*640 + 512 + o] + a3);
    }
    __syncthreads();
    for (int idx = tid; idx < 4*128; idx += NTHR) {
      int br = idx >> 7, rr = idx & 127, b = b0 + br;
      int slot = (t < MD) ? t : selbuf[b];
      hmem[((size_t)b*MD + slot)*RD + rr] = sm.wv[br*128 + rr];
    }
  }
}

extern "C" void kernel_launch(void* const* d_in, const int* in_sizes, int n_in,
                              void* d_out, int out_size, void* d_ws, size_t ws_size,
                              hipStream_t stream) {
  const float* x         = (const float*)d_in[0];
  const float* noise     = (const float*)d_in[1];
  const float* W_full    = (const float*)d_in[2];
  const float* bias      = (const float*)d_in[3];
  const float* W_full1   = (const float*)d_in[4];
  const float* bias1     = (const float*)d_in[5];
  const float* fc_w      = (const float*)d_in[6];
  const float* fc_b      = (const float*)d_in[7];
  const float* trans_w   = (const float*)d_in[8];
  const float* trans_b   = (const float*)d_in[9];
  const float* c_bias    = (const float*)d_in[10];
  const float* hmem_bias = (const float*)d_in[11];
  float* out = (float*)d_out;
  float* ws  = (float*)d_ws;

  k_pre  <<<dim3(256),  dim3(NTHR), 0, stream>>>(fc_w, trans_w, c_bias, hmem_bias, ws);
  k_score<<<dim3(4096), dim3(NTHR), 0, stream>>>(x, noise, fc_b, ws + OFF_FXT, out);
  for (int t = 0; t < TT; ++t) {
    k_gates1  <<<dim3(280), dim3(NTHR), 0, stream>>>(x, W_full1, out, ws, t);
    k_pre_gemm<<<dim3(476), dim3(NTHR), 0, stream>>>(x, W_full, bias1, ws, t);
    k_epi     <<<dim3(64),  dim3(NTHR), 0, stream>>>(bias, trans_b, out, ws, t);
  }
}

// Round 3
// 38273.016 us; speedup vs baseline: 4.2914x; 4.2914x over previous
//
#include <hip/hip_runtime.h>
#include <cmath>

// MARNN scan v3 — no atomics. Per step t:
//   K_A: argmax + h_ent gather + gates1 GEMM (K-split x2, single-writer fp32
//        partials, fp64 register-fold accumulation)
//   K_B: pre GEMM with on-the-fly gating (K-split x2, same accumulation)
//   K_C: epilogue (LSTM cell, outputs, wv/head GEMVs fp64, hmem update)
// Scores (argmax input) for all t precomputed in fp64, stashed in
// out[t,b,512:640]; K_C(t) adds the c-contribution for score(t+1) and then
// k_epi overwrites out[t] with the real outputs.

#define TT 256
#define BB 256
#define XD 256
#define HD 512
#define RD 128
#define MD 128
#define N1 640    // R + H      (gates1 width)
#define NP 2176   // R + 4H     (pre width)

// ---- ws layout (float offsets) — 5,964,288 floats = 23.86 MiB (same as v2) ----
#define OFF_C     0u         // cbuf  [B,H]
#define OFF_HMEM  131072u    // hmem  [B,M,R]
#define OFF_HENT  4325376u   // h_ent [B,R]
#define OFF_SEL   4358144u   // selbuf[B] int
#define OFF_FXT   4358400u   // fcxT  [256,128]  fc_w[:, :256]^T
#define OFF_TWT   4391168u   // transT[512,128]  trans_w^T
#define OFF_FWT   4456704u   // fcwcT [512,128]  fc_w[:,256:768]^T
#define OFF_HEAD0 4522240u   // head0 [M] double
#define OFF_G1P   4522496u   // g1 partials  float [2][B,N1]
#define OFF_PREP  4850176u   // pre partials float [2][B,NP]

__device__ __forceinline__ float sigm(float z){ return 1.0f/(1.0f + expf(-z)); }
__device__ __forceinline__ float4 ld4(const float* p){ return *(const float4*)p; }

// ---------- init: state, transposes, head0 (fp64) ----------
__global__ __launch_bounds__(256)
void k_pre(const float* __restrict__ fc_w, const float* __restrict__ trans_w,
           const float* __restrict__ c_bias, const float* __restrict__ hmem_bias,
           float* __restrict__ ws)
{
  float*  cbuf   = ws + OFF_C;
  float*  hmem   = ws + OFF_HMEM;
  float*  fcxT   = ws + OFF_FXT;
  float*  transT = ws + OFF_TWT;
  float*  fcwcT  = ws + OFF_FWT;
  double* head0d = (double*)(ws + OFF_HEAD0);

  const int gt = blockIdx.x*256 + threadIdx.x, GT = gridDim.x*256;
  for (int i = gt; i < BB*HD;    i += GT) cbuf[i] = (float)tanh((double)c_bias[i & 511]);
  for (int i = gt; i < BB*MD*RD; i += GT) hmem[i] = hmem_bias[i & (MD*RD - 1)];
  for (int i = gt; i < XD*128;   i += GT) { int k=i>>7, m=i&127; fcxT[i]  = fc_w[(size_t)m*768 + k]; }
  for (int i = gt; i < HD*128;   i += GT) { int k=i>>7, o=i&127; transT[i] = trans_w[(size_t)o*512 + k];
                                            fcwcT[i]  = fc_w[(size_t)o*768 + 256 + k]; }
  if (blockIdx.x == 0 && threadIdx.x < 128) {
    double a = 0.0;
    for (int k = 0; k < 512; ++k)
      a += tanh((double)c_bias[k]) * (double)fc_w[(size_t)threadIdx.x*768 + 256 + k];
    head0d[threadIdx.x] = a;
  }
}

// ---------- score: out[t,b,512+m] = fp64(x-part head + fc_b + gumbel) ----------
__global__ __launch_bounds__(256)
void k_score(const float* __restrict__ x, const float* __restrict__ noise,
             const float* __restrict__ fc_b, const float* __restrict__ ws_fcxT,
             float* __restrict__ out)
{
  __shared__ float xs[16*256];
  const int tid = threadIdx.x;
  const int rbase = blockIdx.x * 16;           // 4096 blocks x 16 rows
  for (int i = tid; i < 16*64; i += 256) {
    int row = i >> 6, kq = (i & 63) << 2;
    *(float4*)&xs[row*256 + kq] = ld4(x + (size_t)(rbase + row)*XD + kq);
  }
  __syncthreads();
  const int m = tid & 127, r0 = (tid >> 7) * 8;
  double acc[8] = {};
  for (int k = 0; k < 256; ++k) {
    double wk = (double)ws_fcxT[k*128 + m];
    #pragma unroll
    for (int r = 0; r < 8; ++r) acc[r] += wk * (double)xs[(r0+r)*256 + k];
  }
  #pragma unroll
  for (int r = 0; r < 8; ++r) {
    size_t grow = (size_t)rbase + r0 + r;
    double g   = (double)noise[grow*MD + m];
    double gum = -log(1e-20 - log(1e-20 + g));
    out[grow*640 + 512 + m] = (float)(acc[r] + (double)fc_b[m] + gum);
  }
}

// ---------- K_A: argmax + gather + gates1 GEMM (80 blocks) ----------
__global__ __launch_bounds__(256)
void k_gates1(const float* __restrict__ x, const float* __restrict__ W_full1,
              const float* __restrict__ out, float* __restrict__ ws, int t)
{
  __shared__ float As[16][68];
  __shared__ float Bs[16][64];
  __shared__ int   sel[64];
  const int tid = threadIdx.x, bid = blockIdx.x;
  const int rt = bid & 3, ct = (bid >> 2) % 10, kc = bid / 40;
  const int r0 = rt*64, n0 = ct*64, kbeg = kc*448;
  const float* cbuf = ws + OFF_C;
  const float* hmem = ws + OFF_HMEM;
  float*  hent  = ws + OFF_HENT;
  int*    selb  = (int*)(ws + OFF_SEL);
  double* head0d= (double*)(ws + OFF_HEAD0);
  float*  g1p   = ws + OFF_G1P + (size_t)kc*BB*N1;

  if (kc == 1) {                               // this K-range touches h_entry
    if (tid < 64) {
      const float* sc = out + ((size_t)t*BB + r0 + tid)*640 + 512;
      int bi = 0;
      if (t == 0) { double best = -1e300;
        for (int m = 0; m < 128; ++m) { double v = (double)sc[m] + head0d[m]; if (v > best) { best = v; bi = m; } } }
      else { float best = -3.4e38f;
        for (int m = 0; m < 128; ++m) { float v = sc[m]; if (v > best) { best = v; bi = m; } } }
      sel[tid] = bi;
    }
    __syncthreads();
    if (ct == 0) {                             // designated writer per row-group
      if (tid < 64) selb[r0 + tid] = sel[tid];
      for (int idx = tid; idx < 64*128; idx += 256) {
        int row = idx >> 7, rr = idx & 127;
        hent[(size_t)(r0+row)*RD + rr] = hmem[((size_t)(r0+row)*MD + sel[row])*RD + rr];
      }
    }
  }

  float  acc[4][4] = {};
  double accd[4][4] = {};
  const int tx = tid & 15, ty = tid >> 4;
  const int arow = tid >> 2, akq = (tid & 3) << 2;
  const int bkk = tid >> 4, bnq = (tid & 15) << 2;

  for (int k0 = kbeg; k0 < kbeg + 448; k0 += 16) {
    __syncthreads();
    { // stage A (k-major transpose)
      int b = r0 + arow, k = k0 + akq;
      float4 v;
      if (k < XD)           v = ld4(x + ((size_t)t*BB + b)*XD + k);
      else if (k < XD + HD) v = ld4(cbuf + (size_t)b*HD + (k - XD));
      else                  v = ld4(hmem + ((size_t)b*MD + sel[arow])*RD + (k - (XD+HD)));
      As[akq+0][arow] = v.x; As[akq+1][arow] = v.y;
      As[akq+2][arow] = v.z; As[akq+3][arow] = v.w;
    }
    *(float4*)&Bs[bkk][bnq] = ld4(W_full1 + (size_t)(k0 + bkk)*N1 + n0 + bnq);
    __syncthreads();
    #pragma unroll
    for (int kk = 0; kk < 16; ++kk) {
      float a[4], b[4];
      *(float4*)a = ld4(&As[kk][ty*4]);
      *(float4*)b = ld4(&Bs[kk][tx*4]);
      #pragma unroll
      for (int i = 0; i < 4; ++i)
        #pragma unroll
        for (int j = 0; j < 4; ++j)
          acc[i][j] = fmaf(a[i], b[j], acc[i][j]);
      if ((kk & 7) == 7) {                     // fp64 fold every 8 k
        #pragma unroll
        for (int i = 0; i < 4; ++i)
          #pragma unroll
          for (int j = 0; j < 4; ++j) { accd[i][j] += (double)acc[i][j]; acc[i][j] = 0.f; }
      }
    }
  }
  #pragma unroll
  for (int i = 0; i < 4; ++i)
    #pragma unroll
    for (int j = 0; j < 4; ++j)
      g1p[(size_t)(r0 + ty*4 + i)*N1 + n0 + tx*4 + j] = (float)accd[i][j];
}

// ---------- K_B: pre GEMM with on-the-fly gating (136 blocks) ----------
__global__ __launch_bounds__(256)
void k_pre_gemm(const float* __restrict__ x, const float* __restrict__ W_full,
                const float* __restrict__ bias1, float* __restrict__ ws, int t)
{
  __shared__ float As[16][68];
  __shared__ float Bs[16][128];
  const int tid = threadIdx.x, bid = blockIdx.x;
  const int rt = bid & 3, ct = (bid >> 2) % 17, kc = bid / 68;
  const int r0 = rt*64, n0 = ct*128, kbeg = kc*448;
  const float* cbuf = ws + OFF_C;
  const float* hent = ws + OFF_HENT;
  const float* g1p0 = ws + OFF_G1P;
  const float* g1p1 = g1p0 + (size_t)BB*N1;
  float* prep = ws + OFF_PREP + (size_t)kc*BB*NP;

  float  acc[4][8] = {};
  double accd[4][8] = {};
  const int tx = tid & 15, ty = tid >> 4;
  const int arow = tid >> 2, akq = (tid & 3) << 2;

  for (int k0 = kbeg; k0 < kbeg + 448; k0 += 16) {
    __syncthreads();
    { // stage A with gating applied at load time
      int b = r0 + arow, k = k0 + akq;
      float4 v;
      if (k < XD) v = ld4(x + ((size_t)t*BB + b)*XD + k);
      else if (k < XD + HD) {
        int j = k - XD;
        v = ld4(cbuf + (size_t)b*HD + j);
        float4 p0 = ld4(g1p0 + (size_t)b*N1 + j);
        float4 p1 = ld4(g1p1 + (size_t)b*N1 + j);
        float4 bb = ld4(bias1 + j);
        v.x *= sigm(p0.x + p1.x + bb.x);
        v.y *= sigm(p0.y + p1.y + bb.y);
        v.z *= sigm(p0.z + p1.z + bb.z);
        v.w *= sigm(p0.w + p1.w + bb.w);
      } else {
        int j = k - (XD + HD);
        v = ld4(hent + (size_t)b*RD + j);
        float4 p0 = ld4(g1p0 + (size_t)b*N1 + 512 + j);
        float4 p1 = ld4(g1p1 + (size_t)b*N1 + 512 + j);
        float4 bb = ld4(bias1 + 512 + j);
        v.x *= sigm(p0.x + p1.x + bb.x);
        v.y *= sigm(p0.y + p1.y + bb.y);
        v.z *= sigm(p0.z + p1.z + bb.z);
        v.w *= sigm(p0.w + p1.w + bb.w);
      }
      As[akq+0][arow] = v.x; As[akq+1][arow] = v.y;
      As[akq+2][arow] = v.z; As[akq+3][arow] = v.w;
    }
    #pragma unroll
    for (int rep = 0; rep < 2; ++rep) {
      int idx = tid + rep*256, kk = idx >> 5, nq = (idx & 31) << 2;
      *(float4*)&Bs[kk][nq] = ld4(W_full + (size_t)(k0 + kk)*NP + n0 + nq);
    }
    __syncthreads();
    #pragma unroll
    for (int kk = 0; kk < 16; ++kk) {
      float a[4], b[8];
      *(float4*)a = ld4(&As[kk][ty*4]);
      *(float4*)&b[0] = ld4(&Bs[kk][tx*8]);
      *(float4*)&b[4] = ld4(&Bs[kk][tx*8 + 4]);
      #pragma unroll
      for (int i = 0; i < 4; ++i)
        #pragma unroll
        for (int j = 0; j < 8; ++j)
          acc[i][j] = fmaf(a[i], b[j], acc[i][j]);
      if ((kk & 7) == 7) {
        #pragma unroll
        for (int i = 0; i < 4; ++i)
          #pragma unroll
          for (int j = 0; j < 8; ++j) { accd[i][j] += (double)acc[i][j]; acc[i][j] = 0.f; }
      }
    }
  }
  #pragma unroll
  for (int i = 0; i < 4; ++i)
    #pragma unroll
    for (int j = 0; j < 8; ++j)
      prep[(size_t)(r0 + ty*4 + i)*NP + n0 + tx*8 + j] = (float)accd[i][j];
}

// ---------- K_C: epilogue (64 blocks x 4 batch rows) ----------
__global__ __launch_bounds__(256)
void k_epi(const float* __restrict__ bias, const float* __restrict__ trans_b,
           float* __restrict__ out, float* __restrict__ ws, int t)
{
  __shared__ float smc[4*512];
  __shared__ float smwv[4*128];
  const int tid = threadIdx.x, b0 = blockIdx.x*4;
  float*  cbuf   = ws + OFF_C;
  float*  hmem   = ws + OFF_HMEM;
  float*  hent   = ws + OFF_HENT;
  int*    selb   = (int*)(ws + OFF_SEL);
  float*  transT = ws + OFF_TWT;
  float*  fcwcT  = ws + OFF_FWT;
  const float* prep0 = ws + OFF_PREP;
  const float* prep1 = prep0 + (size_t)BB*NP;

  for (int idx = tid; idx < 4*512; idx += 256) {
    int br = idx >> 9, hh = idx & 511, b = b0 + br;
    const float* p0 = prep0 + (size_t)b*NP;
    const float* p1 = prep1 + (size_t)b*NP;
    float iv = p0[hh]        + p1[hh]        + bias[hh];
    float jv = p0[512 + hh]  + p1[512 + hh]  + bias[512 + hh];
    float fv = p0[1024 + hh] + p1[1024 + hh] + bias[1024 + hh];
    float ov = p0[1536 + hh] + p1[1536 + hh] + bias[1536 + hh];
    float cold = cbuf[(size_t)b*HD + hh];
    float nc = tanhf(cold*sigm(fv + 1.0f) + sigm(iv)*tanhf(jv));
    cbuf[(size_t)b*HD + hh] = nc;
    smc[br*512 + hh] = nc;
    out[((size_t)t*BB + b)*640 + hh] = nc * sigm(ov);
  }
  for (int idx = tid; idx < 4*128; idx += 256) {
    int br = idx >> 7, rr = idx & 127, b = b0 + br;
    float om = prep0[(size_t)b*NP + 2048 + rr] + prep1[(size_t)b*NP + 2048 + rr] + bias[2048 + rr];
    out[((size_t)t*BB + b)*640 + 512 + rr] = hent[(size_t)b*RD + rr] * sigm(om);
  }
  __syncthreads();
  if (t < TT-1) {
    // wv = new_c @ trans_w^T + trans_b ;  score(t+1) += new_c @ fc_wc^T   (fp64)
    int o = tid & 127, mat = tid >> 7;
    const float* WT = mat ? fcwcT : transT;
    double a0=0., a1=0., a2=0., a3=0.;
    for (int k = 0; k < 512; k += 4) {
      float w0 = WT[(k+0)*128 + o], w1 = WT[(k+1)*128 + o];
      float w2 = WT[(k+2)*128 + o], w3 = WT[(k+3)*128 + o];
      float4 c0v = ld4(&smc[0*512 + k]);
      float4 c1v = ld4(&smc[1*512 + k]);
      float4 c2v = ld4(&smc[2*512 + k]);
      float4 c3v = ld4(&smc[3*512 + k]);
      a0 += (double)w0*c0v.x + (double)w1*c0v.y + (double)w2*c0v.z + (double)w3*c0v.w;
      a1 += (double)w0*c1v.x + (double)w1*c1v.y + (double)w2*c1v.z + (double)w3*c1v.w;
      a2 += (double)w0*c2v.x + (double)w1*c2v.y + (double)w2*c2v.z + (double)w3*c2v.w;
      a3 += (double)w0*c3v.x + (double)w1*c3v.y + (double)w2*c3v.z + (double)w3*c3v.w;
    }
    if (mat == 0) {
      smwv[0*128+o] = (float)(a0 + (double)trans_b[o]);
      smwv[1*128+o] = (float)(a1 + (double)trans_b[o]);
      smwv[2*128+o] = (float)(a2 + (double)trans_b[o]);
      smwv[3*128+o] = (float)(a3 + (double)trans_b[o]);
    } else {
      float* sx = out + ((size_t)(t+1)*BB)*640;
      sx[(size_t)(b0+0)*640 + 512 + o] = (float)((double)sx[(size_t)(b0+0)*640 + 512 + o] + a0);
      sx[(size_t)(b0+1)*640 + 512 + o] = (float)((double)sx[(size_t)(b0+1)*640 + 512 + o] + a1);
      sx[(size_t)(b0+2)*640 + 512 + o] = (float)((double)sx[(size_t)(b0+2)*640 + 512 + o] + a2);
      sx[(size_t)(b0+3)*640 + 512 + o] = (float)((double)sx[(size_t)(b0+3)*640 + 512 + o] + a3);
    }
    __syncthreads();
    for (int idx = tid; idx < 4*128; idx += 256) {
      int br = idx >> 7, rr = idx & 127, b = b0 + br;
      int slot = (t < MD) ? t : selb[b];
      hmem[((size_t)b*MD + slot)*RD + rr] = smwv[br*128 + rr];
    }
  }
}

extern "C" void kernel_launch(void* const* d_in, const int* in_sizes, int n_in,
                              void* d_out, int out_size, void* d_ws, size_t ws_size,
                              hipStream_t stream) {
  const float* x         = (const float*)d_in[0];
  const float* noise     = (const float*)d_in[1];
  const float* W_full    = (const float*)d_in[2];
  const float* bias      = (const float*)d_in[3];
  const float* W_full1   = (const float*)d_in[4];
  const float* bias1     = (const float*)d_in[5];
  const float* fc_w      = (const float*)d_in[6];
  const float* fc_b      = (const float*)d_in[7];
  const float* trans_w   = (const float*)d_in[8];
  const float* trans_b   = (const float*)d_in[9];
  const float* c_bias    = (const float*)d_in[10];
  const float* hmem_bias = (const float*)d_in[11];
  float* out = (float*)d_out;
  float* ws  = (float*)d_ws;

  k_pre  <<<dim3(256),  dim3(256), 0, stream>>>(fc_w, trans_w, c_bias, hmem_bias, ws);
  k_score<<<dim3(4096), dim3(256), 0, stream>>>(x, noise, fc_b, ws + OFF_FXT, out);
  for (int t = 0; t < TT; ++t) {
    k_gates1  <<<dim3(80),  dim3(256), 0, stream>>>(x, W_full1, out, ws, t);
    k_pre_gemm<<<dim3(136), dim3(256), 0, stream>>>(x, W_full, bias1, ws, t);
    k_epi     <<<dim3(64),  dim3(256), 0, stream>>>(bias, trans_b, out, ws, t);
  }
}